// Round 12
// baseline (594.265 us; speedup 1.0000x reference)
//
#include <hip/hip_runtime.h>

#define N_NODES 10000
#define N_EDGES 160000
#define CIN 64
#define COUT 128
#define KTOT 125
#define NBINS (N_NODES * KTOT)          // 1,250,000
#define NPAIRS (N_EDGES * 8)            // 1,280,000
#define EPS 1e-5f
#define SPL 12                          // conv1 K-split slices (252/12=21 exact)
#define SPL2 24                         // conv2 K-split slices (504/24=21 exact)
#define CH 5000                         // conv1 chunk rows
#define CH2 2500                        // conv2 chunk rows (accb2 = 80 MB, L3 probe)
#define NSCB 40                         // scan blocks = CDIV(10000,256)

#define CDIV(a,b) (((a)+(b)-1)/(b))

typedef __attribute__((ext_vector_type(8))) short short8;
typedef __attribute__((ext_vector_type(4))) float floatx4;

static __device__ __forceinline__ unsigned short f2b(float f) {
  union { float f; unsigned u; } v; v.f = f;
  unsigned r = v.u + 0x7FFFu + ((v.u >> 16) & 1u);
  return (unsigned short)(r >> 16);
}
static __device__ __forceinline__ float b2f(unsigned short u) {
  union { unsigned u; float f; } v; v.u = ((unsigned)u) << 16;
  return v.f;
}

typedef __attribute__((address_space(1))) const unsigned int guint;
typedef __attribute__((address_space(3))) unsigned int luint;
static __device__ __forceinline__ void ld_g2l16(const void* g, void* l) {
  __builtin_amdgcn_global_load_lds((guint*)g, (luint*)l, 16, 0, 0);
}

// ---------------- edge CSR (dst-sorted edge order) ----------
__global__ void ecount(const int* __restrict__ dst, int* __restrict__ ecnt, int E) {
  int e = blockIdx.x * 256 + threadIdx.x;
  if (e < E) atomicAdd(&ecnt[dst[e]], 1);
}

// ---- parallel scan, phase 1: per-block inclusive scan + block sums ----
__global__ __launch_bounds__(256) void scan_blocks(const int* __restrict__ cnt,
                                                   int* __restrict__ rowptr,
                                                   int* __restrict__ cur,
                                                   int* __restrict__ bsum, int n) {
  int tid = threadIdx.x, lane = tid & 63, w = tid >> 6;
  int i = blockIdx.x * 256 + tid;
  int v = (i < n) ? cnt[i] : 0;
  int s = v;
#pragma unroll
  for (int d = 1; d < 64; d <<= 1) {
    int t = __shfl_up(s, d, 64);
    if (lane >= d) s += t;
  }
  __shared__ int ws[4];
  if (lane == 63) ws[w] = s;
  __syncthreads();
  int add = 0;
#pragma unroll
  for (int j = 0; j < 3; j++) if (w > j) add += ws[j];
  s += add;
  if (i < n) {
    rowptr[i + 1] = s;        // local inclusive (offset added in phase 2)
    cur[i] = s - v;           // local exclusive
  }
  if (tid == 255) bsum[blockIdx.x] = s;
}

// ---- parallel scan, phase 2: add block offsets; absorb escan's side duties ----
__global__ __launch_bounds__(256) void scan_finish(int* __restrict__ rowptr,
                                                   int* __restrict__ cur,
                                                   const int* __restrict__ bsum, int n,
                                                   int* __restrict__ rowptr2,
                                                   float* __restrict__ stats) {
  int b = blockIdx.x, tid = threadIdx.x;
  __shared__ int offs;
  if (tid < 64) {
    int vb = (tid < b) ? bsum[tid] : 0;   // b <= 40 < 64
#pragma unroll
    for (int d = 32; d >= 1; d >>= 1) vb += __shfl_xor(vb, d, 64);
    if (tid == 0) offs = vb;
  }
  if (b == 0) {
    for (int j = tid; j < 6 * 128; j += 256) stats[j] = 0.f;
    if (tid == 0) { rowptr[0] = 0; rowptr2[NBINS] = NPAIRS; }
  }
  __syncthreads();
  int off = offs;
  int i = b * 256 + tid;
  if (i < n) {
    rowptr[i + 1] += off;
    cur[i] += off;
  }
}

__global__ void efill(const int* __restrict__ dst, int* __restrict__ ecur,
                      int* __restrict__ eorder, int E) {
  int e = blockIdx.x * 256 + threadIdx.x;
  if (e >= E) return;
  int pos = atomicAdd(&ecur[dst[e]], 1);
  eorder[pos] = e;
}

// ---------------- build_pairs: one wave per node ----------------
__global__ __launch_bounds__(256) void build_pairs(
    const int* __restrict__ eorder, const int* __restrict__ erowptr,
    const int* __restrict__ src, const float* __restrict__ attr,
    int* __restrict__ rowptr2, int2* __restrict__ pairs) {
  __shared__ int hist_s[4][126];
  __shared__ int cur_s[4][126];
  int w = threadIdx.x >> 6, lane = threadIdx.x & 63;
  int node = blockIdx.x * 4 + w;
  if (node >= N_NODES) return;
  int* hist = hist_s[w];
  int* cur = cur_s[w];
  hist[lane] = 0;
  if (lane < 61) hist[64 + lane] = 0;
  __builtin_amdgcn_s_waitcnt(0);
  int e0 = erowptr[node], e1 = erowptr[node + 1];
  int deg = e1 - e0;
  float invdeg = 1.0f / fmaxf((float)deg, 1.0f);
  int sub_e = lane >> 3, corner = lane & 7;
  int bit0 = corner & 1, bit1 = (corner >> 1) & 1, bit2 = (corner >> 2) & 1;
  for (int base = 0; base < deg; base += 8) {
    int ei = base + sub_e;
    if (ei < deg) {
      int e = eorder[e0 + ei];
      float v0 = attr[e * 3 + 0] * 4.f;
      float v1 = attr[e * 3 + 1] * 4.f;
      float v2 = attr[e * 3 + 2] * 4.f;
      int i0 = (int)floorf(v0), i1 = (int)floorf(v1), i2 = (int)floorf(v2);
      int k0 = min(max(i0 + bit0, 0), 4);
      int k1 = min(max(i1 + bit1, 0), 4);
      int k2 = min(max(i2 + bit2, 0), 4);
      atomicAdd(&hist[k0 * 25 + k1 * 5 + k2], 1);
    }
  }
  __builtin_amdgcn_s_waitcnt(0);
  int v0 = hist[lane];
  int v1 = (lane < 61) ? hist[64 + lane] : 0;
  int s0 = v0;
#pragma unroll
  for (int d = 1; d < 64; d <<= 1) {
    int t = __shfl_up(s0, d, 64);
    if (lane >= d) s0 += t;
  }
  int excl0 = s0 - v0;
  int tot0 = __shfl(s0, 63, 64);
  int s1 = v1;
#pragma unroll
  for (int d = 1; d < 64; d <<= 1) {
    int t = __shfl_up(s1, d, 64);
    if (lane >= d) s1 += t;
  }
  int excl1 = s1 - v1 + tot0;
  int basep = e0 * 8;
  long rbase = (long)node * KTOT;
  rowptr2[rbase + lane] = basep + excl0;
  cur[lane] = basep + excl0;
  if (lane < 61) {
    rowptr2[rbase + 64 + lane] = basep + excl1;
    cur[64 + lane] = basep + excl1;
  }
  __builtin_amdgcn_s_waitcnt(0);
  for (int base = 0; base < deg; base += 8) {
    int ei = base + sub_e;
    if (ei < deg) {
      int e = eorder[e0 + ei];
      float v0f = attr[e * 3 + 0] * 4.f;
      float v1f = attr[e * 3 + 1] * 4.f;
      float v2f = attr[e * 3 + 2] * 4.f;
      float b0f = floorf(v0f), b1f = floorf(v1f), b2f_ = floorf(v2f);
      float f0 = v0f - b0f, f1 = v1f - b1f, f2 = v2f - b2f_;
      int i0 = (int)b0f, i1 = (int)b1f, i2 = (int)b2f_;
      float wv = (bit0 ? f0 : 1.f - f0) * (bit1 ? f1 : 1.f - f1) * (bit2 ? f2 : 1.f - f2);
      int k0 = min(max(i0 + bit0, 0), 4);
      int k1 = min(max(i1 + bit1, 0), 4);
      int k2 = min(max(i2 + bit2, 0), 4);
      int pos = atomicAdd(&cur[k0 * 25 + k1 * 5 + k2], 1);
      int2 rec; rec.x = src[e]; rec.y = __float_as_int(wv * invdeg);
      pairs[pos] = rec;
    }
  }
}

// ---------------- weight transpose: LDS-tiled, coalesced both sides -------------
__global__ __launch_bounds__(256) void transpose_w(const float* __restrict__ src,
                                                   unsigned short* __restrict__ dst,
                                                   int K) {
  __shared__ unsigned short t[128][66];   // stride 66 shorts = 33 dwords (odd) -> conflict-free
  int k0 = blockIdx.x * 64;
  int c = threadIdx.x & 127, r2 = threadIdx.x >> 7;   // 2 k-rows per iteration
#pragma unroll 4
  for (int it = 0; it < 32; ++it) {
    int k = k0 + it * 2 + r2;
    t[c][k - k0] = f2b(src[(long)k * 128 + c]);
  }
  __syncthreads();
  int cc = threadIdx.x >> 1, half = threadIdx.x & 1;
  unsigned short* d = dst + (long)cc * K + k0 + half * 32;
#pragma unroll
  for (int j = 0; j < 32; j += 8) {
    short8 v;
#pragma unroll
    for (int u = 0; u < 8; u++) v[u] = (short)t[cc][half * 32 + j + u];
    *(short8*)(d + j) = v;
  }
}

// ---------------- misc converts: xb + small roots + Wsc broadcast ---------------
__global__ void convert_misc(const float* __restrict__ x, const float* __restrict__ Wr1,
                             const float* __restrict__ Wrsc, const float* __restrict__ Wr2,
                             const float* __restrict__ Wsc,
                             unsigned short* __restrict__ xb, unsigned short* __restrict__ W1aug,
                             unsigned short* __restrict__ rootBt, unsigned short* __restrict__ Wr2t) {
  long i = (long)blockIdx.x * 256 + threadIdx.x;
  const long n0 = 640000, n1 = n0 + 8192, n2 = n1 + 8192, n3 = n2 + 16384,
             n4 = n3 + 16000;
  if (i < n0) {
    xb[i] = f2b(x[i]);
  } else if (i < n1) {
    long j = i - n0; int k = (int)(j >> 7), c = (int)(j & 127);
    rootBt[c * 64 + k] = f2b(Wr1[j]);
  } else if (i < n2) {
    long j = i - n1; int k = (int)(j >> 7), c = (int)(j & 127);
    rootBt[(128 + c) * 64 + k] = f2b(Wrsc[j]);
  } else if (i < n3) {
    long j = i - n2; int k = (int)(j >> 7), c = (int)(j & 127);
    Wr2t[c * 128 + k] = f2b(Wr2[j]);
  } else if (i < n4) {
    long j = i - n3;
    int c = (int)(j / 125), chunk = (int)(j % 125);
    unsigned short* d = W1aug + (long)(128 + c) * 8000 + chunk * 64;
#pragma unroll
    for (int jj = 0; jj < 64; jj += 8) {
      short8 v;
#pragma unroll
      for (int u = 0; u < 8; u++) v[u] = (short)f2b(Wsc[(jj + u) * 128 + c]);
      *(short8*)(d + jj) = v;
    }
  }
}

// ---------------- scatter: phase-split loads, 16B-per-lane memory ops -----------
template<int C>
__global__ __launch_bounds__(256) void scatter_bins(
    const unsigned short* __restrict__ Xb, const int* __restrict__ rowptr2,
    const int2* __restrict__ pairs,
    unsigned short* __restrict__ accb, int bin0, int nbins_chunk) {
  int wb0 = (blockIdx.x * 4 + (threadIdx.x >> 6)) * 8;
  if (wb0 >= nbins_chunk) return;
  int lane = threadIdx.x & 63;
  int bin = bin0 + wb0;
  int bounds = 0;
  if (lane < 9) bounds = rowptr2[bin + lane];
  int b[9];
#pragma unroll
  for (int j = 0; j < 9; j++) b[j] = __shfl(bounds, j, 64);

  if (C == 64) {
    int q = lane >> 3, c8 = lane & 7;
    int pA = b[q], pB = b[q + 1];
    int2 r0 = pairs[(pA < pB) ? pA : 0];
    int2 r1 = pairs[(pA + 1 < pB) ? (pA + 1) : 0];
    short8 g0 = *(const short8*)(Xb + (long)r0.x * 64 + c8 * 8);
    short8 g1 = *(const short8*)(Xb + (long)r1.x * 64 + c8 * 8);
    float w0 = (pA < pB) ? __int_as_float(r0.y) : 0.f;
    float w1 = (pA + 1 < pB) ? __int_as_float(r1.y) : 0.f;
    float f[8];
#pragma unroll
    for (int j = 0; j < 8; j++)
      f[j] = w0 * b2f((unsigned short)g0[j]) + w1 * b2f((unsigned short)g1[j]);
    for (int p = pA + 2; p < pB; p++) {
      int2 r = pairs[p];
      float w = __int_as_float(r.y);
      short8 g = *(const short8*)(Xb + (long)r.x * 64 + c8 * 8);
#pragma unroll
      for (int j = 0; j < 8; j++) f[j] += w * b2f((unsigned short)g[j]);
    }
    int wb = wb0 + q;
    if (wb < nbins_chunk) {
      short8 pk;
#pragma unroll
      for (int j = 0; j < 8; j++) pk[j] = (short)f2b(f[j]);
      *(short8*)(accb + (long)wb * 64 + c8 * 8) = pk;
    }
  } else {
    int q4 = lane >> 4, c16 = lane & 15;
    int pA[2], pB[2];
#pragma unroll
    for (int j = 0; j < 2; j++) {
      pA[j] = b[j * 4 + q4];
      pB[j] = b[j * 4 + q4 + 1];
    }
    int2 r0[2], r1[2];
#pragma unroll
    for (int j = 0; j < 2; j++) {
      r0[j] = pairs[(pA[j] < pB[j]) ? pA[j] : 0];
      r1[j] = pairs[(pA[j] + 1 < pB[j]) ? (pA[j] + 1) : 0];
    }
    short8 g0[2], g1[2];
#pragma unroll
    for (int j = 0; j < 2; j++) {
      g0[j] = *(const short8*)(Xb + (long)r0[j].x * 128 + c16 * 8);
      g1[j] = *(const short8*)(Xb + (long)r1[j].x * 128 + c16 * 8);
    }
#pragma unroll
    for (int j = 0; j < 2; j++) {
      float w0 = (pA[j] < pB[j]) ? __int_as_float(r0[j].y) : 0.f;
      float w1 = (pA[j] + 1 < pB[j]) ? __int_as_float(r1[j].y) : 0.f;
      float f[8];
#pragma unroll
      for (int k = 0; k < 8; k++)
        f[k] = w0 * b2f((unsigned short)g0[j][k]) + w1 * b2f((unsigned short)g1[j][k]);
      for (int p = pA[j] + 2; p < pB[j]; p++) {
        int2 r = pairs[p];
        float w = __int_as_float(r.y);
        short8 g = *(const short8*)(Xb + (long)r.x * 128 + c16 * 8);
#pragma unroll
        for (int k = 0; k < 8; k++) f[k] += w * b2f((unsigned short)g[k]);
      }
      int wb = wb0 + j * 4 + q4;
      if (wb < nbins_chunk) {
        short8 pk;
#pragma unroll
        for (int k = 0; k < 8; k++) pk[k] = (short)f2b(f[k]);
        *(short8*)(accb + (long)wb * 128 + c16 * 8) = pk;
      }
    }
  }
}

// ---------------- depth-4 counted-vmcnt MFMA GEMM, 128 cols, K-extension --------
template<int NCOLS, int EC>
__global__ __launch_bounds__(256, 2) void gemm_tile(
    const unsigned short* __restrict__ A, const unsigned short* __restrict__ Aext,
    const unsigned short* __restrict__ Bt, const unsigned short* __restrict__ Bext,
    float* __restrict__ Cp, int M, int KSP) {
  __shared__ unsigned short As[4][128 * 32];
  __shared__ unsigned short Bs[4][128 * 32];
  int wid = threadIdx.x >> 6, lane = threadIdx.x & 63;
  int row0 = blockIdx.x * 128;
  int Ktot = KSP + EC;
  int nslice = gridDim.y;
  int kslice = CDIV(Ktot / 32, nslice) * 32;
  int kbeg = blockIdx.y * kslice;
  int kend = kbeg + kslice; if (kend > Ktot) kend = Ktot;
  if (kbeg >= Ktot) return;
  int nsteps = (kend - kbeg) >> 5;
  float* C = Cp + (long)blockIdx.y * M * NCOLS;

  int subsw = (lane & 3) ^ ((lane >> 3) & 3);
  int rload = lane >> 2;
  int q = lane >> 4, m16 = lane & 15;
  int sw8 = (q ^ ((m16 >> 1) & 3)) * 8;

  floatx4 acc[2][8];
#pragma unroll
  for (int t = 0; t < 2; t++)
#pragma unroll
    for (int c = 0; c < 8; c++) acc[t][c] = (floatx4){0.f, 0.f, 0.f, 0.f};

  auto stage = [&](int slot, int k0) {
    bool sp = (k0 < KSP);
    int ke = sp ? k0 : (k0 - KSP);
#pragma unroll
    for (int j = 0; j < 2; j++) {
      int tr = (wid * 2 + j) * 16 + rload;
      int gr = row0 + tr; if (gr >= M) gr = M - 1;
      const unsigned short* ap = sp ? (A + (long)gr * KSP + ke + subsw * 8)
                                    : (Aext + (long)gr * EC + ke + subsw * 8);
      const unsigned short* bp = sp ? (Bt + (long)tr * KSP + ke + subsw * 8)
                                    : (Bext + (long)tr * EC + ke + subsw * 8);
      ld_g2l16(ap, &As[slot][(wid * 2 + j) * 512]);
      ld_g2l16(bp, &Bs[slot][(wid * 2 + j) * 512]);
    }
  };

  stage(0, kbeg);
  if (nsteps > 1) stage(1, kbeg + 32);
  if (nsteps > 2) stage(2, kbeg + 64);
  int cons = 0, stg = 3;
  for (int t = 0; t < nsteps; ++t) {
    int nfut = nsteps - 1 - t;
    if (nfut >= 2) {
      asm volatile("s_waitcnt vmcnt(8)" ::: "memory");
    } else if (nfut == 1) {
      asm volatile("s_waitcnt vmcnt(4)" ::: "memory");
    } else {
      asm volatile("s_waitcnt vmcnt(0)" ::: "memory");
    }
    __builtin_amdgcn_s_barrier();
    __builtin_amdgcn_sched_barrier(0);
    if (t + 3 < nsteps) stage(stg, kbeg + (t + 3) * 32);
    const unsigned short* Ac = &As[cons][0];
    const unsigned short* Bc = &Bs[cons][0];
    short8 a0 = *(const short8*)(Ac + (wid * 32 + m16) * 32 + sw8);
    short8 a1 = *(const short8*)(Ac + (wid * 32 + 16 + m16) * 32 + sw8);
#pragma unroll
    for (int c = 0; c < 8; c++) {
      short8 b = *(const short8*)(Bc + (c * 16 + m16) * 32 + sw8);
      acc[0][c] = __builtin_amdgcn_mfma_f32_16x16x32_bf16(a0, b, acc[0][c], 0, 0, 0);
      acc[1][c] = __builtin_amdgcn_mfma_f32_16x16x32_bf16(a1, b, acc[1][c], 0, 0, 0);
    }
    __builtin_amdgcn_sched_barrier(0);
    cons = (cons + 1) & 3;
    stg = (stg + 1) & 3;
  }

#pragma unroll
  for (int t = 0; t < 2; t++) {
#pragma unroll
    for (int c = 0; c < 8; c++) {
#pragma unroll
      for (int r = 0; r < 4; r++) {
        int orow = row0 + wid * 32 + t * 16 + q * 4 + r;
        if (orow < M) C[(long)orow * NCOLS + c * 16 + m16] = acc[t][c][r];
      }
    }
  }
}

// ---------------- 128x256 tile GEMM, depth-3 counted-vmcnt, partial-C -----------
template<int EC>
__global__ __launch_bounds__(256, 2) void gemm_tile_w256(
    const unsigned short* __restrict__ A, const unsigned short* __restrict__ Aext,
    const unsigned short* __restrict__ Bt, const unsigned short* __restrict__ Bext,
    float* __restrict__ Cp, int M, int KSP) {
  __shared__ unsigned short As[3][128 * 32];
  __shared__ unsigned short Bs[3][256 * 32];
  int wid = threadIdx.x >> 6, lane = threadIdx.x & 63;
  int row0 = blockIdx.x * 128;
  int Ktot = KSP + EC;
  int nslice = gridDim.y;
  int kslice = CDIV(Ktot / 32, nslice) * 32;
  int kbeg = blockIdx.y * kslice;
  int kend = kbeg + kslice; if (kend > Ktot) kend = Ktot;
  if (kbeg >= Ktot) return;
  int nsteps = (kend - kbeg) >> 5;
  float* C = Cp + (long)blockIdx.y * M * 256;

  int subsw = (lane & 3) ^ ((lane >> 3) & 3);
  int rload = lane >> 2;
  int q = lane >> 4, m16 = lane & 15;
  int sw8 = (q ^ ((m16 >> 1) & 3)) * 8;

  floatx4 acc[2][16];
#pragma unroll
  for (int t = 0; t < 2; t++)
#pragma unroll
    for (int c = 0; c < 16; c++) acc[t][c] = (floatx4){0.f, 0.f, 0.f, 0.f};

  auto stage = [&](int slot, int k0) {
    bool sp = (k0 < KSP);
    int ke = sp ? k0 : (k0 - KSP);
#pragma unroll
    for (int j = 0; j < 2; j++) {
      int tr = (wid * 2 + j) * 16 + rload;
      int gr = row0 + tr; if (gr >= M) gr = M - 1;
      const unsigned short* ap = sp ? (A + (long)gr * KSP + ke + subsw * 8)
                                    : (Aext + (long)gr * EC + ke + subsw * 8);
      ld_g2l16(ap, &As[slot][(wid * 2 + j) * 512]);
    }
#pragma unroll
    for (int j = 0; j < 4; j++) {
      int tr = (wid * 4 + j) * 16 + rload;
      const unsigned short* bp = sp ? (Bt + (long)tr * KSP + ke + subsw * 8)
                                    : (Bext + (long)tr * EC + ke + subsw * 8);
      ld_g2l16(bp, &Bs[slot][(wid * 4 + j) * 512]);
    }
  };

  stage(0, kbeg);
  if (nsteps > 1) stage(1, kbeg + 32);
  int cons = 0, stg = 2;
  for (int t = 0; t < nsteps; ++t) {
    if (t + 1 < nsteps) {
      asm volatile("s_waitcnt vmcnt(6)" ::: "memory");
    } else {
      asm volatile("s_waitcnt vmcnt(0)" ::: "memory");
    }
    __builtin_amdgcn_s_barrier();
    __builtin_amdgcn_sched_barrier(0);
    if (t + 2 < nsteps) stage(stg, kbeg + (t + 2) * 32);
    const unsigned short* Ac = &As[cons][0];
    const unsigned short* Bc = &Bs[cons][0];
    short8 a0 = *(const short8*)(Ac + (wid * 32 + m16) * 32 + sw8);
    short8 a1 = *(const short8*)(Ac + (wid * 32 + 16 + m16) * 32 + sw8);
#pragma unroll
    for (int c = 0; c < 16; c++) {
      short8 b = *(const short8*)(Bc + (c * 16 + m16) * 32 + sw8);
      acc[0][c] = __builtin_amdgcn_mfma_f32_16x16x32_bf16(a0, b, acc[0][c], 0, 0, 0);
      acc[1][c] = __builtin_amdgcn_mfma_f32_16x16x32_bf16(a1, b, acc[1][c], 0, 0, 0);
    }
    __builtin_amdgcn_sched_barrier(0);
    if (++cons == 3) cons = 0;
    if (++stg == 3) stg = 0;
  }

#pragma unroll
  for (int t = 0; t < 2; t++) {
#pragma unroll
    for (int c = 0; c < 16; c++) {
#pragma unroll
      for (int r = 0; r < 4; r++) {
        int orow = row0 + wid * 32 + t * 16 + q * 4 + r;
        if (orow < M) C[(long)orow * 256 + c * 16 + m16] = acc[t][c][r];
      }
    }
  }
}

// ---------------- per-chunk slice reductions -------
__global__ void reduce_finalize1(const float* __restrict__ P, const float* __restrict__ bias,
                                 const float* __restrict__ bsc,
                                 float* __restrict__ h1, float* __restrict__ sraw,
                                 float* __restrict__ stats, float* __restrict__ statssc,
                                 int cm, int c0) {
  int c = threadIdx.x;                  // i & 255 == tid (stride multiple of 256)
  float bv = (c < 128) ? bias[c] : bsc[c - 128];
  float s = 0.f, s2 = 0.f;
  long tot = (long)cm * 256;
  for (long i = (long)blockIdx.x * 256 + threadIdx.x; i < tot; i += (long)gridDim.x * 256) {
    int r = (int)(i >> 8);
    float v = 0.f;
#pragma unroll
    for (int sl = 0; sl < SPL; sl++) v += P[((long)sl * cm + r) * 256 + c];
    v += bv;
    if (c < 128) h1[(long)(c0 + r) * 128 + c] = v;
    else         sraw[(long)(c0 + r) * 128 + (c - 128)] = v;
    s += v; s2 += v * v;
  }
  if (c < 128) {
    atomicAdd(&stats[c], s);
    atomicAdd(&stats[128 + c], s2);
  } else {
    atomicAdd(&statssc[c - 128], s);
    atomicAdd(&statssc[c], s2);       // c-128+128 == c
  }
}

__global__ void reduce_finalize2(const float* __restrict__ P, const float* __restrict__ b2,
                                 float* __restrict__ h2r, float* __restrict__ stats2,
                                 int cm, int c0) {
  int c = threadIdx.x & 127;            // i & 127 == tid & 127
  float bv2 = b2[c];
  float sa = 0.f, sb = 0.f;
  long tot = (long)cm * 128;
  for (long i = (long)blockIdx.x * 256 + threadIdx.x; i < tot; i += (long)gridDim.x * 256) {
    int r = (int)(i >> 7);
    float v2 = 0.f;
#pragma unroll
    for (int sl = 0; sl < SPL2; sl++) v2 += P[((long)sl * cm + r) * 128 + c];
    v2 += bv2;
    h2r[(long)(c0 + r) * 128 + c] = v2;
    sa += v2; sb += v2 * v2;
  }
  atomicAdd(&stats2[c], sa);
  atomicAdd(&stats2[128 + c], sb);
}

__global__ void bn_elu_kernel(float* __restrict__ h, unsigned short* __restrict__ hb,
                              const float* __restrict__ stats, const float* __restrict__ g,
                              const float* __restrict__ be, int n) {
  long i = (long)blockIdx.x * 256 + threadIdx.x;
  if (i >= (long)n * COUT) return;
  int c = (int)(i & 127);
  float inv_n = 1.0f / n;
  float mu = stats[c] * inv_n;
  float var = stats[128 + c] * inv_n - mu * mu;
  float v = (h[i] - mu) * rsqrtf(var + EPS) * g[c] + be[c];
  v = v > 0.f ? v : expm1f(v);
  h[i] = v;
  hb[i] = f2b(v);
}

__global__ void final_out_kernel(const float* __restrict__ h2, const float* __restrict__ sraw,
                                 const float* __restrict__ st2, const float* __restrict__ stsc,
                                 const float* __restrict__ g2, const float* __restrict__ be2,
                                 const float* __restrict__ gsc, const float* __restrict__ besc,
                                 float* __restrict__ out, int n) {
  long i = (long)blockIdx.x * 256 + threadIdx.x;
  if (i >= (long)n * COUT) return;
  int c = (int)(i & 127);
  float inv_n = 1.0f / n;
  float mu2 = st2[c] * inv_n;
  float var2 = st2[128 + c] * inv_n - mu2 * mu2;
  float a = (h2[i] - mu2) * rsqrtf(var2 + EPS) * g2[c] + be2[c];
  float musc = stsc[c] * inv_n;
  float varsc = stsc[128 + c] * inv_n - musc * musc;
  float b = (sraw[i] - musc) * rsqrtf(varsc + EPS) * gsc[c] + besc[c];
  float v = a + b;
  out[i] = v > 0.f ? v : expm1f(v);
}

// ---------------- host ----------------
extern "C" void kernel_launch(void* const* d_in, const int* in_sizes, int n_in,
                              void* d_out, int out_size, void* d_ws, size_t ws_size,
                              hipStream_t stream) {
  const float* x    = (const float*)d_in[0];
  const int*   eidx = (const int*)d_in[1];
  const float* attr = (const float*)d_in[2];
  const float* W1   = (const float*)d_in[3];
  const float* Wr1  = (const float*)d_in[4];
  const float* b1   = (const float*)d_in[5];
  const float* g1   = (const float*)d_in[6];
  const float* be1  = (const float*)d_in[7];
  const float* W2   = (const float*)d_in[8];
  const float* Wr2  = (const float*)d_in[9];
  const float* b2   = (const float*)d_in[10];
  const float* g2   = (const float*)d_in[11];
  const float* be2  = (const float*)d_in[12];
  const float* Wsc  = (const float*)d_in[13];
  const float* Wrsc = (const float*)d_in[14];
  const float* bsc  = (const float*)d_in[15];
  const float* gsc  = (const float*)d_in[16];
  const float* besc = (const float*)d_in[17];
  float* out = (float*)d_out;

  const int* src = eidx;
  const int* dst = eidx + N_EDGES;

  char* base = (char*)d_ws;
  size_t off = 0;
  auto alloc = [&](size_t bytes) -> char* {
    char* p = base + off;
    off += (bytes + 255) & ~(size_t)255;
    return p;
  };
  int* ecnt   = (int*)alloc((size_t)N_NODES * 4);
  int* erowptr= (int*)alloc((size_t)(N_NODES + 1) * 4);
  int* ecur   = (int*)alloc((size_t)N_NODES * 4);
  int* eorder = (int*)alloc((size_t)N_EDGES * 4);
  int* bsum   = (int*)alloc((size_t)NSCB * 4);
  int* rowptr2= (int*)alloc((size_t)(NBINS + 1) * 4);
  int2* pairs = (int2*)alloc((size_t)NPAIRS * 8);
  unsigned short* xb    = (unsigned short*)alloc((size_t)N_NODES * CIN * 2);
  unsigned short* hb    = (unsigned short*)alloc((size_t)N_NODES * COUT * 2);
  unsigned short* W1aug = (unsigned short*)alloc((size_t)256 * KTOT * CIN * 2);
  unsigned short* W2t   = (unsigned short*)alloc((size_t)COUT * KTOT * COUT * 2);
  unsigned short* rootBt= (unsigned short*)alloc((size_t)256 * CIN * 2);
  unsigned short* Wr2t  = (unsigned short*)alloc((size_t)COUT * COUT * 2);
  float* h1    = (float*)alloc((size_t)N_NODES * COUT * 4);
  float* h2r   = (float*)alloc((size_t)N_NODES * COUT * 4);
  float* sraw  = (float*)alloc((size_t)N_NODES * COUT * 4);
  float* stats = (float*)alloc(6 * 128 * 4);
  // tail: accb chunk + per-chunk partial-C slabs (overlap-free by construction)
  char* tail = base + off;
  unsigned short* accb = (unsigned short*)tail;
  const size_t ACCB1 = (size_t)CH  * KTOT * CIN  * 2;   // 80,000,000 (256-aligned)
  const size_t ACCB2 = (size_t)CH2 * KTOT * COUT * 2;   // 80,000,000 (256-aligned)
  float* P1 = (float*)(tail + ACCB1);   // SPL  * CH  * 256 * 4 = 61.4 MB
  float* P2 = (float*)(tail + ACCB2);   // SPL2 * CH2 * 128 * 4 = 30.7 MB
  (void)ws_size;

  hipMemsetAsync(ecnt, 0, (size_t)N_NODES * 4, stream);

  // edge CSR: dst-sorted edge permutation (parallel 2-phase scan)
  ecount<<<CDIV(N_EDGES, 256), 256, 0, stream>>>(dst, ecnt, N_EDGES);
  scan_blocks<<<NSCB, 256, 0, stream>>>(ecnt, erowptr, ecur, bsum, N_NODES);
  scan_finish<<<NSCB, 256, 0, stream>>>(erowptr, ecur, bsum, N_NODES, rowptr2, stats);
  efill<<<CDIV(N_EDGES, 256), 256, 0, stream>>>(dst, ecur, eorder, N_EDGES);

  // per-node pair build (weights carry 1/deg)
  build_pairs<<<CDIV(N_NODES, 4), 256, 0, stream>>>(eorder, erowptr, src, attr,
                                                    rowptr2, pairs);

  // weight converts: coalesced LDS-tiled transposes + misc
  transpose_w<<<8000 / 64, 256, 0, stream>>>(W1, W1aug, 8000);
  transpose_w<<<16000 / 64, 256, 0, stream>>>(W2, W2t, 16000);
  const long MISC_TOT = 640000L + 8192 + 8192 + 16384 + 16000;
  convert_misc<<<CDIV(MISC_TOT, 256), 256, 0, stream>>>(x, Wr1, Wrsc, Wr2, Wsc,
                                                        xb, W1aug, rootBt, Wr2t);

  // ---- conv1 + shortcut spline + both root GEMMs, chunked, partial-C ----
  for (int c0 = 0; c0 < N_NODES; c0 += CH) {
    int cm = (N_NODES - c0 < CH) ? (N_NODES - c0) : CH;
    int nbc = cm * KTOT;
    scatter_bins<64><<<CDIV(nbc, 32), 256, 0, stream>>>(xb, rowptr2, pairs, accb,
                                                        c0 * KTOT, nbc);
    dim3 g(CDIV(cm, 128), SPL);
    gemm_tile_w256<64><<<g, 256, 0, stream>>>(
        accb, xb + (size_t)c0 * CIN, W1aug, rootBt, P1, cm, KTOT * CIN);
    reduce_finalize1<<<96, 256, 0, stream>>>(P1, b1, bsc, h1, sraw, stats,
                                             stats + 512, cm, c0);
  }
  bn_elu_kernel<<<CDIV(N_NODES * COUT, 256), 256, 0, stream>>>(h1, hb, stats, g1, be1, N_NODES);

  // ---- conv2 + root GEMM, small chunks (accb2 = 80 MB -> L3 handoff probe) ----
  for (int c0 = 0; c0 < N_NODES; c0 += CH2) {
    int cm = (N_NODES - c0 < CH2) ? (N_NODES - c0) : CH2;
    int nbc = cm * KTOT;
    scatter_bins<128><<<CDIV(nbc, 32), 256, 0, stream>>>(hb, rowptr2, pairs, accb,
                                                         c0 * KTOT, nbc);
    dim3 g(CDIV(cm, 128), SPL2);
    gemm_tile<COUT, 128><<<g, 256, 0, stream>>>(
        accb, hb + (size_t)c0 * COUT, W2t, Wr2t, P2, cm, KTOT * COUT);
    reduce_finalize2<<<96, 256, 0, stream>>>(P2, b2, h2r, stats + 256, cm, c0);
  }

  // ---- output ----
  final_out_kernel<<<CDIV(N_NODES * COUT, 256), 256, 0, stream>>>(
      h2r, sraw, stats + 256, stats + 512, g2, be2, gsc, besc, out, N_NODES);
}

// Round 13
// 544.643 us; speedup vs baseline: 1.0911x; 1.0911x over previous
//
#include <hip/hip_runtime.h>

#define N_NODES 10000
#define N_EDGES 160000
#define CIN 64
#define COUT 128
#define KTOT 125
#define NBINS (N_NODES * KTOT)          // 1,250,000
#define NPAIRS (N_EDGES * 8)            // 1,280,000
#define EPS 1e-5f
#define SPL 12                          // conv1 K-split slices (252/12=21 exact)
#define SPL2 12                         // conv2 K-split slices (504/12=42 exact)
#define CH 5000                         // chunk rows (2 chunks; best-measured R11)
#define NSCB 40                         // scan blocks = CDIV(10000,256)

#define CDIV(a,b) (((a)+(b)-1)/(b))

typedef __attribute__((ext_vector_type(8))) short short8;
typedef __attribute__((ext_vector_type(4))) float floatx4;

static __device__ __forceinline__ unsigned short f2b(float f) {
  union { float f; unsigned u; } v; v.f = f;
  unsigned r = v.u + 0x7FFFu + ((v.u >> 16) & 1u);
  return (unsigned short)(r >> 16);
}
static __device__ __forceinline__ float b2f(unsigned short u) {
  union { unsigned u; float f; } v; v.u = ((unsigned)u) << 16;
  return v.f;
}

typedef __attribute__((address_space(1))) const unsigned int guint;
typedef __attribute__((address_space(3))) unsigned int luint;
static __device__ __forceinline__ void ld_g2l16(const void* g, void* l) {
  __builtin_amdgcn_global_load_lds((guint*)g, (luint*)l, 16, 0, 0);
}

// ---------------- edge CSR (dst-sorted edge order) ----------
__global__ void ecount(const int* __restrict__ dst, int* __restrict__ ecnt, int E) {
  int e = blockIdx.x * 256 + threadIdx.x;
  if (e < E) atomicAdd(&ecnt[dst[e]], 1);
}

// ---- parallel scan, phase 1: per-block inclusive scan + block sums ----
__global__ __launch_bounds__(256) void scan_blocks(const int* __restrict__ cnt,
                                                   int* __restrict__ rowptr,
                                                   int* __restrict__ cur,
                                                   int* __restrict__ bsum, int n) {
  int tid = threadIdx.x, lane = tid & 63, w = tid >> 6;
  int i = blockIdx.x * 256 + tid;
  int v = (i < n) ? cnt[i] : 0;
  int s = v;
#pragma unroll
  for (int d = 1; d < 64; d <<= 1) {
    int t = __shfl_up(s, d, 64);
    if (lane >= d) s += t;
  }
  __shared__ int ws[4];
  if (lane == 63) ws[w] = s;
  __syncthreads();
  int add = 0;
#pragma unroll
  for (int j = 0; j < 3; j++) if (w > j) add += ws[j];
  s += add;
  if (i < n) {
    rowptr[i + 1] = s;        // local inclusive (offset added in phase 2)
    cur[i] = s - v;           // local exclusive
  }
  if (tid == 255) bsum[blockIdx.x] = s;
}

// ---- parallel scan, phase 2: add block offsets; absorb escan's side duties ----
__global__ __launch_bounds__(256) void scan_finish(int* __restrict__ rowptr,
                                                   int* __restrict__ cur,
                                                   const int* __restrict__ bsum, int n,
                                                   int* __restrict__ rowptr2,
                                                   float* __restrict__ stats) {
  int b = blockIdx.x, tid = threadIdx.x;
  __shared__ int offs;
  if (tid < 64) {
    int vb = (tid < b) ? bsum[tid] : 0;   // b <= 40 < 64
#pragma unroll
    for (int d = 32; d >= 1; d >>= 1) vb += __shfl_xor(vb, d, 64);
    if (tid == 0) offs = vb;
  }
  if (b == 0) {
    for (int j = tid; j < 6 * 128; j += 256) stats[j] = 0.f;
    if (tid == 0) { rowptr[0] = 0; rowptr2[NBINS] = NPAIRS; }
  }
  __syncthreads();
  int off = offs;
  int i = b * 256 + tid;
  if (i < n) {
    rowptr[i + 1] += off;
    cur[i] += off;
  }
}

__global__ void efill(const int* __restrict__ dst, int* __restrict__ ecur,
                      int* __restrict__ eorder, int E) {
  int e = blockIdx.x * 256 + threadIdx.x;
  if (e >= E) return;
  int pos = atomicAdd(&ecur[dst[e]], 1);
  eorder[pos] = e;
}

// ---------------- build_pairs: one wave per node ----------------
__global__ __launch_bounds__(256) void build_pairs(
    const int* __restrict__ eorder, const int* __restrict__ erowptr,
    const int* __restrict__ src, const float* __restrict__ attr,
    int* __restrict__ rowptr2, int2* __restrict__ pairs) {
  __shared__ int hist_s[4][126];
  __shared__ int cur_s[4][126];
  int w = threadIdx.x >> 6, lane = threadIdx.x & 63;
  int node = blockIdx.x * 4 + w;
  if (node >= N_NODES) return;
  int* hist = hist_s[w];
  int* cur = cur_s[w];
  hist[lane] = 0;
  if (lane < 61) hist[64 + lane] = 0;
  __builtin_amdgcn_s_waitcnt(0);
  int e0 = erowptr[node], e1 = erowptr[node + 1];
  int deg = e1 - e0;
  float invdeg = 1.0f / fmaxf((float)deg, 1.0f);
  int sub_e = lane >> 3, corner = lane & 7;
  int bit0 = corner & 1, bit1 = (corner >> 1) & 1, bit2 = (corner >> 2) & 1;
  for (int base = 0; base < deg; base += 8) {
    int ei = base + sub_e;
    if (ei < deg) {
      int e = eorder[e0 + ei];
      float v0 = attr[e * 3 + 0] * 4.f;
      float v1 = attr[e * 3 + 1] * 4.f;
      float v2 = attr[e * 3 + 2] * 4.f;
      int i0 = (int)floorf(v0), i1 = (int)floorf(v1), i2 = (int)floorf(v2);
      int k0 = min(max(i0 + bit0, 0), 4);
      int k1 = min(max(i1 + bit1, 0), 4);
      int k2 = min(max(i2 + bit2, 0), 4);
      atomicAdd(&hist[k0 * 25 + k1 * 5 + k2], 1);
    }
  }
  __builtin_amdgcn_s_waitcnt(0);
  int v0 = hist[lane];
  int v1 = (lane < 61) ? hist[64 + lane] : 0;
  int s0 = v0;
#pragma unroll
  for (int d = 1; d < 64; d <<= 1) {
    int t = __shfl_up(s0, d, 64);
    if (lane >= d) s0 += t;
  }
  int excl0 = s0 - v0;
  int tot0 = __shfl(s0, 63, 64);
  int s1 = v1;
#pragma unroll
  for (int d = 1; d < 64; d <<= 1) {
    int t = __shfl_up(s1, d, 64);
    if (lane >= d) s1 += t;
  }
  int excl1 = s1 - v1 + tot0;
  int basep = e0 * 8;
  long rbase = (long)node * KTOT;
  rowptr2[rbase + lane] = basep + excl0;
  cur[lane] = basep + excl0;
  if (lane < 61) {
    rowptr2[rbase + 64 + lane] = basep + excl1;
    cur[64 + lane] = basep + excl1;
  }
  __builtin_amdgcn_s_waitcnt(0);
  for (int base = 0; base < deg; base += 8) {
    int ei = base + sub_e;
    if (ei < deg) {
      int e = eorder[e0 + ei];
      float v0f = attr[e * 3 + 0] * 4.f;
      float v1f = attr[e * 3 + 1] * 4.f;
      float v2f = attr[e * 3 + 2] * 4.f;
      float b0f = floorf(v0f), b1f = floorf(v1f), b2f_ = floorf(v2f);
      float f0 = v0f - b0f, f1 = v1f - b1f, f2 = v2f - b2f_;
      int i0 = (int)b0f, i1 = (int)b1f, i2 = (int)b2f_;
      float wv = (bit0 ? f0 : 1.f - f0) * (bit1 ? f1 : 1.f - f1) * (bit2 ? f2 : 1.f - f2);
      int k0 = min(max(i0 + bit0, 0), 4);
      int k1 = min(max(i1 + bit1, 0), 4);
      int k2 = min(max(i2 + bit2, 0), 4);
      int pos = atomicAdd(&cur[k0 * 25 + k1 * 5 + k2], 1);
      int2 rec; rec.x = src[e]; rec.y = __float_as_int(wv * invdeg);
      pairs[pos] = rec;
    }
  }
}

// ---------------- weight transpose: LDS-tiled, coalesced both sides -------------
__global__ __launch_bounds__(256) void transpose_w(const float* __restrict__ src,
                                                   unsigned short* __restrict__ dst,
                                                   int K) {
  __shared__ unsigned short t[128][66];   // stride 66 shorts = 33 dwords (odd) -> conflict-free
  int k0 = blockIdx.x * 64;
  int c = threadIdx.x & 127, r2 = threadIdx.x >> 7;   // 2 k-rows per iteration
#pragma unroll 4
  for (int it = 0; it < 32; ++it) {
    int k = k0 + it * 2 + r2;
    t[c][k - k0] = f2b(src[(long)k * 128 + c]);
  }
  __syncthreads();
  int cc = threadIdx.x >> 1, half = threadIdx.x & 1;
  unsigned short* d = dst + (long)cc * K + k0 + half * 32;
#pragma unroll
  for (int j = 0; j < 32; j += 8) {
    short8 v;
#pragma unroll
    for (int u = 0; u < 8; u++) v[u] = (short)t[cc][half * 32 + j + u];
    *(short8*)(d + j) = v;
  }
}

// ---------------- misc converts: xb + small roots + Wsc broadcast ---------------
__global__ void convert_misc(const float* __restrict__ x, const float* __restrict__ Wr1,
                             const float* __restrict__ Wrsc, const float* __restrict__ Wr2,
                             const float* __restrict__ Wsc,
                             unsigned short* __restrict__ xb, unsigned short* __restrict__ W1aug,
                             unsigned short* __restrict__ rootBt, unsigned short* __restrict__ Wr2t) {
  long i = (long)blockIdx.x * 256 + threadIdx.x;
  const long n0 = 640000, n1 = n0 + 8192, n2 = n1 + 8192, n3 = n2 + 16384,
             n4 = n3 + 16000;
  if (i < n0) {
    xb[i] = f2b(x[i]);
  } else if (i < n1) {
    long j = i - n0; int k = (int)(j >> 7), c = (int)(j & 127);
    rootBt[c * 64 + k] = f2b(Wr1[j]);
  } else if (i < n2) {
    long j = i - n1; int k = (int)(j >> 7), c = (int)(j & 127);
    rootBt[(128 + c) * 64 + k] = f2b(Wrsc[j]);
  } else if (i < n3) {
    long j = i - n2; int k = (int)(j >> 7), c = (int)(j & 127);
    Wr2t[c * 128 + k] = f2b(Wr2[j]);
  } else if (i < n4) {
    long j = i - n3;
    int c = (int)(j / 125), chunk = (int)(j % 125);
    unsigned short* d = W1aug + (long)(128 + c) * 8000 + chunk * 64;
#pragma unroll
    for (int jj = 0; jj < 64; jj += 8) {
      short8 v;
#pragma unroll
      for (int u = 0; u < 8; u++) v[u] = (short)f2b(Wsc[(jj + u) * 128 + c]);
      *(short8*)(d + jj) = v;
    }
  }
}

// ---------------- scatter: phase-split loads, 16B-per-lane memory ops -----------
template<int C>
__global__ __launch_bounds__(256) void scatter_bins(
    const unsigned short* __restrict__ Xb, const int* __restrict__ rowptr2,
    const int2* __restrict__ pairs,
    unsigned short* __restrict__ accb, int bin0, int nbins_chunk) {
  int wb0 = (blockIdx.x * 4 + (threadIdx.x >> 6)) * 8;
  if (wb0 >= nbins_chunk) return;
  int lane = threadIdx.x & 63;
  int bin = bin0 + wb0;
  int bounds = 0;
  if (lane < 9) bounds = rowptr2[bin + lane];
  int b[9];
#pragma unroll
  for (int j = 0; j < 9; j++) b[j] = __shfl(bounds, j, 64);

  if (C == 64) {
    int q = lane >> 3, c8 = lane & 7;
    int pA = b[q], pB = b[q + 1];
    int2 r0 = pairs[(pA < pB) ? pA : 0];
    int2 r1 = pairs[(pA + 1 < pB) ? (pA + 1) : 0];
    short8 g0 = *(const short8*)(Xb + (long)r0.x * 64 + c8 * 8);
    short8 g1 = *(const short8*)(Xb + (long)r1.x * 64 + c8 * 8);
    float w0 = (pA < pB) ? __int_as_float(r0.y) : 0.f;
    float w1 = (pA + 1 < pB) ? __int_as_float(r1.y) : 0.f;
    float f[8];
#pragma unroll
    for (int j = 0; j < 8; j++)
      f[j] = w0 * b2f((unsigned short)g0[j]) + w1 * b2f((unsigned short)g1[j]);
    for (int p = pA + 2; p < pB; p++) {
      int2 r = pairs[p];
      float w = __int_as_float(r.y);
      short8 g = *(const short8*)(Xb + (long)r.x * 64 + c8 * 8);
#pragma unroll
      for (int j = 0; j < 8; j++) f[j] += w * b2f((unsigned short)g[j]);
    }
    int wb = wb0 + q;
    if (wb < nbins_chunk) {
      short8 pk;
#pragma unroll
      for (int j = 0; j < 8; j++) pk[j] = (short)f2b(f[j]);
      *(short8*)(accb + (long)wb * 64 + c8 * 8) = pk;
    }
  } else {
    int q4 = lane >> 4, c16 = lane & 15;
    int pA[2], pB[2];
#pragma unroll
    for (int j = 0; j < 2; j++) {
      pA[j] = b[j * 4 + q4];
      pB[j] = b[j * 4 + q4 + 1];
    }
    int2 r0[2], r1[2];
#pragma unroll
    for (int j = 0; j < 2; j++) {
      r0[j] = pairs[(pA[j] < pB[j]) ? pA[j] : 0];
      r1[j] = pairs[(pA[j] + 1 < pB[j]) ? (pA[j] + 1) : 0];
    }
    short8 g0[2], g1[2];
#pragma unroll
    for (int j = 0; j < 2; j++) {
      g0[j] = *(const short8*)(Xb + (long)r0[j].x * 128 + c16 * 8);
      g1[j] = *(const short8*)(Xb + (long)r1[j].x * 128 + c16 * 8);
    }
#pragma unroll
    for (int j = 0; j < 2; j++) {
      float w0 = (pA[j] < pB[j]) ? __int_as_float(r0[j].y) : 0.f;
      float w1 = (pA[j] + 1 < pB[j]) ? __int_as_float(r1[j].y) : 0.f;
      float f[8];
#pragma unroll
      for (int k = 0; k < 8; k++)
        f[k] = w0 * b2f((unsigned short)g0[j][k]) + w1 * b2f((unsigned short)g1[j][k]);
      for (int p = pA[j] + 2; p < pB[j]; p++) {
        int2 r = pairs[p];
        float w = __int_as_float(r.y);
        short8 g = *(const short8*)(Xb + (long)r.x * 128 + c16 * 8);
#pragma unroll
        for (int k = 0; k < 8; k++) f[k] += w * b2f((unsigned short)g[k]);
      }
      int wb = wb0 + j * 4 + q4;
      if (wb < nbins_chunk) {
        short8 pk;
#pragma unroll
        for (int k = 0; k < 8; k++) pk[k] = (short)f2b(f[k]);
        *(short8*)(accb + (long)wb * 128 + c16 * 8) = pk;
      }
    }
  }
}

// ---------------- depth-4 counted-vmcnt MFMA GEMM, 128 cols, K-extension --------
template<int NCOLS, int EC>
__global__ __launch_bounds__(256, 2) void gemm_tile(
    const unsigned short* __restrict__ A, const unsigned short* __restrict__ Aext,
    const unsigned short* __restrict__ Bt, const unsigned short* __restrict__ Bext,
    float* __restrict__ Cp, int M, int KSP) {
  __shared__ unsigned short As[4][128 * 32];
  __shared__ unsigned short Bs[4][128 * 32];
  int wid = threadIdx.x >> 6, lane = threadIdx.x & 63;
  int row0 = blockIdx.x * 128;
  int Ktot = KSP + EC;
  int nslice = gridDim.y;
  int kslice = CDIV(Ktot / 32, nslice) * 32;
  int kbeg = blockIdx.y * kslice;
  int kend = kbeg + kslice; if (kend > Ktot) kend = Ktot;
  if (kbeg >= Ktot) return;
  int nsteps = (kend - kbeg) >> 5;
  float* C = Cp + (long)blockIdx.y * M * NCOLS;

  int subsw = (lane & 3) ^ ((lane >> 3) & 3);
  int rload = lane >> 2;
  int q = lane >> 4, m16 = lane & 15;
  int sw8 = (q ^ ((m16 >> 1) & 3)) * 8;

  floatx4 acc[2][8];
#pragma unroll
  for (int t = 0; t < 2; t++)
#pragma unroll
    for (int c = 0; c < 8; c++) acc[t][c] = (floatx4){0.f, 0.f, 0.f, 0.f};

  auto stage = [&](int slot, int k0) {
    bool sp = (k0 < KSP);
    int ke = sp ? k0 : (k0 - KSP);
#pragma unroll
    for (int j = 0; j < 2; j++) {
      int tr = (wid * 2 + j) * 16 + rload;
      int gr = row0 + tr; if (gr >= M) gr = M - 1;
      const unsigned short* ap = sp ? (A + (long)gr * KSP + ke + subsw * 8)
                                    : (Aext + (long)gr * EC + ke + subsw * 8);
      const unsigned short* bp = sp ? (Bt + (long)tr * KSP + ke + subsw * 8)
                                    : (Bext + (long)tr * EC + ke + subsw * 8);
      ld_g2l16(ap, &As[slot][(wid * 2 + j) * 512]);
      ld_g2l16(bp, &Bs[slot][(wid * 2 + j) * 512]);
    }
  };

  stage(0, kbeg);
  if (nsteps > 1) stage(1, kbeg + 32);
  if (nsteps > 2) stage(2, kbeg + 64);
  int cons = 0, stg = 3;
  for (int t = 0; t < nsteps; ++t) {
    int nfut = nsteps - 1 - t;
    if (nfut >= 2) {
      asm volatile("s_waitcnt vmcnt(8)" ::: "memory");
    } else if (nfut == 1) {
      asm volatile("s_waitcnt vmcnt(4)" ::: "memory");
    } else {
      asm volatile("s_waitcnt vmcnt(0)" ::: "memory");
    }
    __builtin_amdgcn_s_barrier();
    __builtin_amdgcn_sched_barrier(0);
    if (t + 3 < nsteps) stage(stg, kbeg + (t + 3) * 32);
    const unsigned short* Ac = &As[cons][0];
    const unsigned short* Bc = &Bs[cons][0];
    short8 a0 = *(const short8*)(Ac + (wid * 32 + m16) * 32 + sw8);
    short8 a1 = *(const short8*)(Ac + (wid * 32 + 16 + m16) * 32 + sw8);
#pragma unroll
    for (int c = 0; c < 8; c++) {
      short8 b = *(const short8*)(Bc + (c * 16 + m16) * 32 + sw8);
      acc[0][c] = __builtin_amdgcn_mfma_f32_16x16x32_bf16(a0, b, acc[0][c], 0, 0, 0);
      acc[1][c] = __builtin_amdgcn_mfma_f32_16x16x32_bf16(a1, b, acc[1][c], 0, 0, 0);
    }
    __builtin_amdgcn_sched_barrier(0);
    cons = (cons + 1) & 3;
    stg = (stg + 1) & 3;
  }

#pragma unroll
  for (int t = 0; t < 2; t++) {
#pragma unroll
    for (int c = 0; c < 8; c++) {
#pragma unroll
      for (int r = 0; r < 4; r++) {
        int orow = row0 + wid * 32 + t * 16 + q * 4 + r;
        if (orow < M) C[(long)orow * NCOLS + c * 16 + m16] = acc[t][c][r];
      }
    }
  }
}

// ---------------- 128x256 tile GEMM, depth-3 counted-vmcnt, partial-C -----------
template<int EC>
__global__ __launch_bounds__(256, 2) void gemm_tile_w256(
    const unsigned short* __restrict__ A, const unsigned short* __restrict__ Aext,
    const unsigned short* __restrict__ Bt, const unsigned short* __restrict__ Bext,
    float* __restrict__ Cp, int M, int KSP) {
  __shared__ unsigned short As[3][128 * 32];
  __shared__ unsigned short Bs[3][256 * 32];
  int wid = threadIdx.x >> 6, lane = threadIdx.x & 63;
  int row0 = blockIdx.x * 128;
  int Ktot = KSP + EC;
  int nslice = gridDim.y;
  int kslice = CDIV(Ktot / 32, nslice) * 32;
  int kbeg = blockIdx.y * kslice;
  int kend = kbeg + kslice; if (kend > Ktot) kend = Ktot;
  if (kbeg >= Ktot) return;
  int nsteps = (kend - kbeg) >> 5;
  float* C = Cp + (long)blockIdx.y * M * 256;

  int subsw = (lane & 3) ^ ((lane >> 3) & 3);
  int rload = lane >> 2;
  int q = lane >> 4, m16 = lane & 15;
  int sw8 = (q ^ ((m16 >> 1) & 3)) * 8;

  floatx4 acc[2][16];
#pragma unroll
  for (int t = 0; t < 2; t++)
#pragma unroll
    for (int c = 0; c < 16; c++) acc[t][c] = (floatx4){0.f, 0.f, 0.f, 0.f};

  auto stage = [&](int slot, int k0) {
    bool sp = (k0 < KSP);
    int ke = sp ? k0 : (k0 - KSP);
#pragma unroll
    for (int j = 0; j < 2; j++) {
      int tr = (wid * 2 + j) * 16 + rload;
      int gr = row0 + tr; if (gr >= M) gr = M - 1;
      const unsigned short* ap = sp ? (A + (long)gr * KSP + ke + subsw * 8)
                                    : (Aext + (long)gr * EC + ke + subsw * 8);
      ld_g2l16(ap, &As[slot][(wid * 2 + j) * 512]);
    }
#pragma unroll
    for (int j = 0; j < 4; j++) {
      int tr = (wid * 4 + j) * 16 + rload;
      const unsigned short* bp = sp ? (Bt + (long)tr * KSP + ke + subsw * 8)
                                    : (Bext + (long)tr * EC + ke + subsw * 8);
      ld_g2l16(bp, &Bs[slot][(wid * 4 + j) * 512]);
    }
  };

  stage(0, kbeg);
  if (nsteps > 1) stage(1, kbeg + 32);
  int cons = 0, stg = 2;
  for (int t = 0; t < nsteps; ++t) {
    if (t + 1 < nsteps) {
      asm volatile("s_waitcnt vmcnt(6)" ::: "memory");
    } else {
      asm volatile("s_waitcnt vmcnt(0)" ::: "memory");
    }
    __builtin_amdgcn_s_barrier();
    __builtin_amdgcn_sched_barrier(0);
    if (t + 2 < nsteps) stage(stg, kbeg + (t + 2) * 32);
    const unsigned short* Ac = &As[cons][0];
    const unsigned short* Bc = &Bs[cons][0];
    short8 a0 = *(const short8*)(Ac + (wid * 32 + m16) * 32 + sw8);
    short8 a1 = *(const short8*)(Ac + (wid * 32 + 16 + m16) * 32 + sw8);
#pragma unroll
    for (int c = 0; c < 16; c++) {
      short8 b = *(const short8*)(Bc + (c * 16 + m16) * 32 + sw8);
      acc[0][c] = __builtin_amdgcn_mfma_f32_16x16x32_bf16(a0, b, acc[0][c], 0, 0, 0);
      acc[1][c] = __builtin_amdgcn_mfma_f32_16x16x32_bf16(a1, b, acc[1][c], 0, 0, 0);
    }
    __builtin_amdgcn_sched_barrier(0);
    if (++cons == 3) cons = 0;
    if (++stg == 3) stg = 0;
  }

#pragma unroll
  for (int t = 0; t < 2; t++) {
#pragma unroll
    for (int c = 0; c < 16; c++) {
#pragma unroll
      for (int r = 0; r < 4; r++) {
        int orow = row0 + wid * 32 + t * 16 + q * 4 + r;
        if (orow < M) C[(long)orow * 256 + c * 16 + m16] = acc[t][c][r];
      }
    }
  }
}

// ---------------- per-chunk slice reductions -------
__global__ void reduce_finalize1(const float* __restrict__ P, const float* __restrict__ bias,
                                 const float* __restrict__ bsc,
                                 float* __restrict__ h1, float* __restrict__ sraw,
                                 float* __restrict__ stats, float* __restrict__ statssc,
                                 int cm, int c0) {
  int c = threadIdx.x;                  // i & 255 == tid (stride multiple of 256)
  float bv = (c < 128) ? bias[c] : bsc[c - 128];
  float s = 0.f, s2 = 0.f;
  long tot = (long)cm * 256;
  for (long i = (long)blockIdx.x * 256 + threadIdx.x; i < tot; i += (long)gridDim.x * 256) {
    int r = (int)(i >> 8);
    float v = 0.f;
#pragma unroll
    for (int sl = 0; sl < SPL; sl++) v += P[((long)sl * cm + r) * 256 + c];
    v += bv;
    if (c < 128) h1[(long)(c0 + r) * 128 + c] = v;
    else         sraw[(long)(c0 + r) * 128 + (c - 128)] = v;
    s += v; s2 += v * v;
  }
  if (c < 128) {
    atomicAdd(&stats[c], s);
    atomicAdd(&stats[128 + c], s2);
  } else {
    atomicAdd(&statssc[c - 128], s);
    atomicAdd(&statssc[c], s2);       // c-128+128 == c
  }
}

__global__ void reduce_finalize2(const float* __restrict__ P, const float* __restrict__ b2,
                                 float* __restrict__ h2r, float* __restrict__ stats2,
                                 int cm, int c0) {
  int c = threadIdx.x & 127;            // i & 127 == tid & 127
  float bv2 = b2[c];
  float sa = 0.f, sb = 0.f;
  long tot = (long)cm * 128;
  for (long i = (long)blockIdx.x * 256 + threadIdx.x; i < tot; i += (long)gridDim.x * 256) {
    int r = (int)(i >> 7);
    float v2 = 0.f;
#pragma unroll
    for (int sl = 0; sl < SPL2; sl++) v2 += P[((long)sl * cm + r) * 128 + c];
    v2 += bv2;
    h2r[(long)(c0 + r) * 128 + c] = v2;
    sa += v2; sb += v2 * v2;
  }
  atomicAdd(&stats2[c], sa);
  atomicAdd(&stats2[128 + c], sb);
}

__global__ void bn_elu_kernel(float* __restrict__ h, unsigned short* __restrict__ hb,
                              const float* __restrict__ stats, const float* __restrict__ g,
                              const float* __restrict__ be, int n) {
  long i = (long)blockIdx.x * 256 + threadIdx.x;
  if (i >= (long)n * COUT) return;
  int c = (int)(i & 127);
  float inv_n = 1.0f / n;
  float mu = stats[c] * inv_n;
  float var = stats[128 + c] * inv_n - mu * mu;
  float v = (h[i] - mu) * rsqrtf(var + EPS) * g[c] + be[c];
  v = v > 0.f ? v : expm1f(v);
  h[i] = v;
  hb[i] = f2b(v);
}

__global__ void final_out_kernel(const float* __restrict__ h2, const float* __restrict__ sraw,
                                 const float* __restrict__ st2, const float* __restrict__ stsc,
                                 const float* __restrict__ g2, const float* __restrict__ be2,
                                 const float* __restrict__ gsc, const float* __restrict__ besc,
                                 float* __restrict__ out, int n) {
  long i = (long)blockIdx.x * 256 + threadIdx.x;
  if (i >= (long)n * COUT) return;
  int c = (int)(i & 127);
  float inv_n = 1.0f / n;
  float mu2 = st2[c] * inv_n;
  float var2 = st2[128 + c] * inv_n - mu2 * mu2;
  float a = (h2[i] - mu2) * rsqrtf(var2 + EPS) * g2[c] + be2[c];
  float musc = stsc[c] * inv_n;
  float varsc = stsc[128 + c] * inv_n - musc * musc;
  float b = (sraw[i] - musc) * rsqrtf(varsc + EPS) * gsc[c] + besc[c];
  float v = a + b;
  out[i] = v > 0.f ? v : expm1f(v);
}

// ---------------- host ----------------
extern "C" void kernel_launch(void* const* d_in, const int* in_sizes, int n_in,
                              void* d_out, int out_size, void* d_ws, size_t ws_size,
                              hipStream_t stream) {
  const float* x    = (const float*)d_in[0];
  const int*   eidx = (const int*)d_in[1];
  const float* attr = (const float*)d_in[2];
  const float* W1   = (const float*)d_in[3];
  const float* Wr1  = (const float*)d_in[4];
  const float* b1   = (const float*)d_in[5];
  const float* g1   = (const float*)d_in[6];
  const float* be1  = (const float*)d_in[7];
  const float* W2   = (const float*)d_in[8];
  const float* Wr2  = (const float*)d_in[9];
  const float* b2   = (const float*)d_in[10];
  const float* g2   = (const float*)d_in[11];
  const float* be2  = (const float*)d_in[12];
  const float* Wsc  = (const float*)d_in[13];
  const float* Wrsc = (const float*)d_in[14];
  const float* bsc  = (const float*)d_in[15];
  const float* gsc  = (const float*)d_in[16];
  const float* besc = (const float*)d_in[17];
  float* out = (float*)d_out;

  const int* src = eidx;
  const int* dst = eidx + N_EDGES;

  char* base = (char*)d_ws;
  size_t off = 0;
  auto alloc = [&](size_t bytes) -> char* {
    char* p = base + off;
    off += (bytes + 255) & ~(size_t)255;
    return p;
  };
  int* ecnt   = (int*)alloc((size_t)N_NODES * 4);
  int* erowptr= (int*)alloc((size_t)(N_NODES + 1) * 4);
  int* ecur   = (int*)alloc((size_t)N_NODES * 4);
  int* eorder = (int*)alloc((size_t)N_EDGES * 4);
  int* bsum   = (int*)alloc((size_t)NSCB * 4);
  int* rowptr2= (int*)alloc((size_t)(NBINS + 1) * 4);
  int2* pairs = (int2*)alloc((size_t)NPAIRS * 8);
  unsigned short* xb    = (unsigned short*)alloc((size_t)N_NODES * CIN * 2);
  unsigned short* hb    = (unsigned short*)alloc((size_t)N_NODES * COUT * 2);
  unsigned short* W1aug = (unsigned short*)alloc((size_t)256 * KTOT * CIN * 2);
  unsigned short* W2t   = (unsigned short*)alloc((size_t)COUT * KTOT * COUT * 2);
  unsigned short* rootBt= (unsigned short*)alloc((size_t)256 * CIN * 2);
  unsigned short* Wr2t  = (unsigned short*)alloc((size_t)COUT * COUT * 2);
  float* h1    = (float*)alloc((size_t)N_NODES * COUT * 4);
  float* h2r   = (float*)alloc((size_t)N_NODES * COUT * 4);
  float* sraw  = (float*)alloc((size_t)N_NODES * COUT * 4);
  float* stats = (float*)alloc(6 * 128 * 4);
  // tail: accb chunk + per-chunk partial-C slabs (overlap-free by construction)
  char* tail = base + off;
  unsigned short* accb = (unsigned short*)tail;
  const size_t ACCB1 = (size_t)CH * KTOT * CIN * 2;    // 80,000,000 (256-aligned)
  const size_t ACCB2 = (size_t)CH * KTOT * COUT * 2;   // 160,000,000 (256-aligned)
  float* P1 = (float*)(tail + ACCB1);   // SPL * CH * 256 * 4 = 61.4 MB
  float* P2 = (float*)(tail + ACCB2);   // SPL2 * CH * 128 * 4 = 30.7 MB
  (void)ws_size;

  hipMemsetAsync(ecnt, 0, (size_t)N_NODES * 4, stream);

  // edge CSR: dst-sorted edge permutation (parallel 2-phase scan)
  ecount<<<CDIV(N_EDGES, 256), 256, 0, stream>>>(dst, ecnt, N_EDGES);
  scan_blocks<<<NSCB, 256, 0, stream>>>(ecnt, erowptr, ecur, bsum, N_NODES);
  scan_finish<<<NSCB, 256, 0, stream>>>(erowptr, ecur, bsum, N_NODES, rowptr2, stats);
  efill<<<CDIV(N_EDGES, 256), 256, 0, stream>>>(dst, ecur, eorder, N_EDGES);

  // per-node pair build (weights carry 1/deg)
  build_pairs<<<CDIV(N_NODES, 4), 256, 0, stream>>>(eorder, erowptr, src, attr,
                                                    rowptr2, pairs);

  // weight converts: coalesced LDS-tiled transposes + misc
  transpose_w<<<8000 / 64, 256, 0, stream>>>(W1, W1aug, 8000);
  transpose_w<<<16000 / 64, 256, 0, stream>>>(W2, W2t, 16000);
  const long MISC_TOT = 640000L + 8192 + 8192 + 16384 + 16000;
  convert_misc<<<CDIV(MISC_TOT, 256), 256, 0, stream>>>(x, Wr1, Wrsc, Wr2, Wsc,
                                                        xb, W1aug, rootBt, Wr2t);

  // ---- conv1 + shortcut spline + both root GEMMs, chunked, partial-C ----
  for (int c0 = 0; c0 < N_NODES; c0 += CH) {
    int cm = (N_NODES - c0 < CH) ? (N_NODES - c0) : CH;
    int nbc = cm * KTOT;
    scatter_bins<64><<<CDIV(nbc, 32), 256, 0, stream>>>(xb, rowptr2, pairs, accb,
                                                        c0 * KTOT, nbc);
    dim3 g(CDIV(cm, 128), SPL);
    gemm_tile_w256<64><<<g, 256, 0, stream>>>(
        accb, xb + (size_t)c0 * CIN, W1aug, rootBt, P1, cm, KTOT * CIN);
    reduce_finalize1<<<96, 256, 0, stream>>>(P1, b1, bsc, h1, sraw, stats,
                                             stats + 512, cm, c0);
  }
  bn_elu_kernel<<<CDIV(N_NODES * COUT, 256), 256, 0, stream>>>(h1, hb, stats, g1, be1, N_NODES);

  // ---- conv2 + root GEMM, chunked, partial-C ----
  for (int c0 = 0; c0 < N_NODES; c0 += CH) {
    int cm = (N_NODES - c0 < CH) ? (N_NODES - c0) : CH;
    int nbc = cm * KTOT;
    scatter_bins<128><<<CDIV(nbc, 32), 256, 0, stream>>>(hb, rowptr2, pairs, accb,
                                                         c0 * KTOT, nbc);
    dim3 g(CDIV(cm, 128), SPL2);
    gemm_tile<COUT, 128><<<g, 256, 0, stream>>>(
        accb, hb + (size_t)c0 * COUT, W2t, Wr2t, P2, cm, KTOT * COUT);
    reduce_finalize2<<<96, 256, 0, stream>>>(P2, b2, h2r, stats + 256, cm, c0);
  }

  // ---- output ----
  final_out_kernel<<<CDIV(N_NODES * COUT, 256), 256, 0, stream>>>(
      h2r, sraw, stats + 256, stats + 512, g2, be2, gsc, besc, out, N_NODES);
}